// Round 2
// baseline (257.643 us; speedup 1.0000x reference)
//
#include <hip/hip_runtime.h>
#include <hip/hip_fp16.h>

// B=64, N=64, D=128, L=4, T=10. Float tensors may arrive as bf16 OR fp32.
// r14: persistent fused network kernel. After prep, batches are fully
// independent; only b16 (the per-batch j-rows of the edge pre-activation)
// crosses blocks. Grid = 256 blocks (4 parts x 64 batches, 16 rows each,
// 512 threads) -> all blocks co-resident (1/CU). Per-batch 4-block flag
// sync (release/acquire, AGENT scope) replaces 9 dispatch boundaries.
// b16 ping-pongs between two buffers (WAR-safe: flag>=4(lay+2) implies all
// parts finished edge(lay) reads). h/a/m live in LDS only. Edge/node math
// verbatim from the proven r10/r13 kernels.

typedef _Float16 f16;
typedef _Float16 f16x8 __attribute__((ext_vector_type(8)));
typedef float f32x4 __attribute__((ext_vector_type(4)));

union H2x4 { f16x8 v; __half2 h[4]; };

__device__ __forceinline__ float bf2f(unsigned short u) {
    union { unsigned int i; float f; } v; v.i = ((unsigned int)u) << 16; return v.f;
}
__device__ __forceinline__ unsigned short f2bf(float f) {
    union { float f; unsigned int i; } v; v.f = f;
    unsigned int x = v.i;
    return (unsigned short)((x + 0x7fffu + ((x >> 16) & 1u)) >> 16);
}
__device__ __forceinline__ float silu_f(float x) {
    float e = __builtin_amdgcn_exp2f(-1.44269504088896f * x);
    return x * __builtin_amdgcn_rcpf(1.0f + e);
}
__device__ __forceinline__ __half2 silu_h2(__half2 x, __half2 kf, __half2 one2) {
    __half2 e = h2exp2(__hmul2(x, kf));
    return __hmul2(x, h2rcp(__hadd2(one2, e)));
}

struct Ptrs { const void* p[14]; };
// p: 0 pos, 1 embed, 2 ew1, 3 eb1, 4 ew2, 5 eb2, 6 nw1, 7 nb1, 8 nw2,
//    9 nb2, 10 lng, 11 lnb, 12 ow, 13 ob

__device__ __forceinline__ float ldf(const void* p, int i, int bf) {
    return bf ? bf2f(((const unsigned short*)p)[i]) : ((const float*)p)[i];
}

// small canon (fp32) offsets: pos 0(12288) embed 12288(1280) wd 13568(512)
// eb1 14080 eb2 14592 nb1 15104 nb2 15616 lng 16128 lnb 16640 (512 each)
// ow 17152(384) ob 17536(3). total 17539.
#define ELEM_TOTAL 393216
#define SMALL_TOTAL 17539

// Swizzle weights into f16 B-fragment order for mfma_f32_16x16x32_f16.
// One thread builds one element:
//   dst[f*8+j] = W[rowoff + s*32 + ((l>>4)<<3) + j][c*16 + (l&15)],
//   f = (s*8+c)*64+l. Per-layer frag bases: wa 0, wb 2048, ew2 4096,
//   nw1 6144, nw2 10240; layer stride 12288 frags.
// Also zeroes the 64 per-batch sync flags (block 0).
__global__ __launch_bounds__(256) void prep_kernel(
    Ptrs ptrs, f16* dst, float* sc, int* flags)
{
    __shared__ int flgsh;
    int t = threadIdx.x;
    if (blockIdx.x == 0 && t < 64) flags[t] = 0;
    if (t < 64) {
        int ex = (((const unsigned short*)ptrs.p[0])[t * 2] >> 7) & 0xFF;
        unsigned long long m = __ballot(ex >= 110 && ex <= 135);
        if (t == 0) flgsh = (__popcll(m) >= 40) ? 1 : 0;
    }
    __syncthreads();
    int bf = flgsh;

    int gid = blockIdx.x * 256 + t;
    if (gid < ELEM_TOTAL) {
        int f = gid >> 3, j = gid & 7;
        int lay = f / 12288;
        int r   = f % 12288;
        const void* src; int base, rowoff = 0, r2;
        if (r < 6144) {
            int mat = r >> 11; r2 = r & 2047;
            if (mat == 0)      { src = ptrs.p[2]; base = lay * 32896; }
            else if (mat == 1) { src = ptrs.p[2]; base = lay * 32896; rowoff = 128; }
            else               { src = ptrs.p[4]; base = lay * 16384; }
        } else if (r < 10240) {
            r2 = r - 6144; src = ptrs.p[6]; base = lay * 32768;
        } else {
            r2 = r - 10240; src = ptrs.p[8]; base = lay * 16384;
        }
        int s = r2 >> 9, c = (r2 >> 6) & 7, l = r2 & 63;
        int row = rowoff + s * 32 + ((l >> 4) << 3) + j;
        int col = (c << 4) + (l & 15);
        dst[gid] = (f16)ldf(src, base + row * 128 + col, bf);
    } else {
        int sid = gid - ELEM_TOTAL;
        if (sid >= SMALL_TOTAL) return;
        const void* src; int i;
        if      (sid < 12288) { src = ptrs.p[0]; i = sid; }
        else if (sid < 13568) { src = ptrs.p[1]; i = sid - 12288; }
        else if (sid < 14080) { int k = sid - 13568;
                                src = ptrs.p[2]; i = (k >> 7) * 32896 + 32768 + (k & 127); }
        else if (sid < 14592) { src = ptrs.p[3];  i = sid - 14080; }
        else if (sid < 15104) { src = ptrs.p[5];  i = sid - 14592; }
        else if (sid < 15616) { src = ptrs.p[7];  i = sid - 15104; }
        else if (sid < 16128) { src = ptrs.p[9];  i = sid - 15616; }
        else if (sid < 16640) { src = ptrs.p[10]; i = sid - 16128; }
        else if (sid < 17152) { src = ptrs.p[11]; i = sid - 16640; }
        else if (sid < 17536) { src = ptrs.p[12]; i = sid - 17152; }
        else                  { src = ptrs.p[13]; i = sid - 17536; }
        sc[sid] = ldf(src, i, bf);
    }
}

// Persistent fused network. Block = (batch b, part p): rows r0..r0+15.
// 512 threads = 8 waves; wave w owns output col tile c = w (16 cols).
__global__ __launch_bounds__(512) void net_kernel(
    const void* pos_raw, const int* an, const float* sc, const f16* Wswz,
    f16* b0, f16* b1, int* flags, void* out)
{
    __shared__ f16 S[2][64 * 136];      // 34.0 KB; S[0] doubles as node relay
    __shared__ f16 a_lds[16 * 136];     // own-row a (incl eb1)
    __shared__ f16 h_lds[16 * 136];     // own-row h
    __shared__ f16 m_lds[16 * 136];     // own-row m
    __shared__ __half dsq2[16][64];     // own dist^2 (f16); aliased as psh at end
    __shared__ __half2 wd2_sh[64];
    __shared__ float s1sh[8][16], s2sh[8][16];
    __shared__ int flgsh;

    int t = threadIdx.x;
    int w = t >> 6, lane = t & 63;
    int m_ = lane & 15, q_ = lane >> 4;
    int c = w;
    int b  = blockIdx.x >> 2;
    int r0 = b * 64 + (blockIdx.x & 3) * 16;
    const float* posC = sc;

    if (t < 64) {
        int ex = (((const unsigned short*)pos_raw)[t * 2] >> 7) & 0xFF;
        unsigned long long mk = __ballot(ex >= 110 && ex <= 135);
        if (t == 0) flgsh = (__popcll(mk) >= 40) ? 1 : 0;
    }
    // dist^2 for own 16 i x 64 j (positions are layer-invariant)
    for (int k = t; k < 1024; k += 512) {
        int ii = k >> 6, j = k & 63;
        int gi = r0 + ii, gj = b * 64 + j;
        float dx = posC[gi * 3 + 0] - posC[gj * 3 + 0];
        float dy = posC[gi * 3 + 1] - posC[gj * 3 + 1];
        float dz = posC[gi * 3 + 2] - posC[gj * 3 + 2];
        dsq2[ii][j] = __float2half_rn(dx * dx + dy * dy + dz * dz);
    }

    // ---- embed + layer-0 a,b ----
    {
        const float* emb  = sc + 12288;
        const float* eb1C = sc + 14080;
        int a = an[r0 + m_];
        a = a < 0 ? 0 : (a > 9 ? 9 : a);
        f16x8 afrag[4];
#pragma unroll
        for (int s = 0; s < 4; s++) {
            f32x4 u0 = *(const f32x4*)(emb + a * 128 + s * 32 + q_ * 8);
            f32x4 u1 = *(const f32x4*)(emb + a * 128 + s * 32 + q_ * 8 + 4);
            f16x8 hv;
#pragma unroll
            for (int e = 0; e < 4; e++) { hv[e] = (f16)u0[e]; hv[e + 4] = (f16)u1[e]; }
            afrag[s] = hv;
            if (w == 0)
                *(f16x8*)(h_lds + m_ * 136 + s * 32 + q_ * 8) = hv;
        }
#pragma unroll
        for (int mat = 0; mat < 2; mat++) {
            const f16* W = mat ? (Wswz + 16384) : Wswz;
            float init = mat ? 0.0f : eb1C[c * 16 + m_];
            f32x4 acc = { init, init, init, init };
#pragma unroll
            for (int s = 0; s < 4; s++) {
                f16x8 bfv = *(const f16x8*)(W + ((s * 8 + c) * 64 + lane) * 8);
                acc = __builtin_amdgcn_mfma_f32_16x16x32_f16(afrag[s], bfv, acc, 0, 0, 0);
            }
#pragma unroll
            for (int r = 0; r < 4; r++) {
                if (mat == 0)
                    a_lds[(q_ * 4 + r) * 136 + c * 16 + m_] = (f16)acc[r];
                else
                    b0[(r0 + q_ * 4 + r) * 128 + c * 16 + m_] = (f16)acc[r];
            }
        }
    }
    __syncthreads();
    if (t == 0) {
        __threadfence();
        __hip_atomic_fetch_add(&flags[b], 1, __ATOMIC_RELEASE,
                               __HIP_MEMORY_SCOPE_AGENT);
    }

    // ---- layers ----
    for (int lay = 0; lay < 4; lay++) {
        const f16* wl   = Wswz + lay * 98304;
        const f16* ew2s = wl + 32768;
        const f16* nw1s = wl + 49152;
        const f16* nw2s = wl + 81920;
        const float* wdC  = sc + 13568 + lay * 128;
        const float* eb2C = sc + 14592 + lay * 128;
        const float* nb1C = sc + 15104 + lay * 128;
        const float* nb2C = sc + 15616 + lay * 128;
        const float* lngC = sc + 16128 + lay * 128;
        const float* lnbC = sc + 16640 + lay * 128;
        const f16* bcur = (lay & 1) ? b1 : b0;
        f16*       bnxt = (lay & 1) ? b0 : b1;

        // acquire: all 4 parts of this batch produced layer-lay a,b
        if (t == 0) {
            int target = 4 * (lay + 1);
            int spins = 0;
            while (__hip_atomic_load(&flags[b], __ATOMIC_ACQUIRE,
                                     __HIP_MEMORY_SCOPE_AGENT) < target) {
                __builtin_amdgcn_s_sleep(8);
                if (++spins > (1 << 20)) break;   // deadlock escape, never hit
            }
        }
        __syncthreads();

        if (t < 64) wd2_sh[t] = __floats2half2_rn(wdC[2 * t], wdC[2 * t + 1]);
        f16x8 bfr[4];
#pragma unroll
        for (int s = 0; s < 4; s++)
            bfr[s] = *(const f16x8*)(ew2s + ((s * 8 + c) * 64 + lane) * 8);
        __syncthreads();

        // ---- edge: m_i for own 16 i ----
        float eb2v = eb2C[c * 16 + m_];
        const __half2 kf   = __floats2half2_rn(-1.44269504f, -1.44269504f);
        const __half2 one2 = __floats2half2_rn(1.0f, 1.0f);
        for (int i = 0; i < 16; i++) {
            f16* Sc = S[i & 1];
            // build S (all 512 threads, 2 chunks each)
#pragma unroll
            for (int k = 0; k < 2; k++) {
                int chunk = t + 512 * k;
                int row = chunk >> 4, col = (chunk & 15) * 8;
                __half dh = dsq2[i][row];
                __half2 ds2 = __halves2half2(dh, dh);
                H2x4 av, bv, wv, sv;
                av.v = *(const f16x8*)(a_lds + i * 136 + col);
                bv.v = *(const f16x8*)(bcur + (b * 64 + row) * 128 + col);
                wv.v = *(const f16x8*)((const f16*)wd2_sh + col);
#pragma unroll
                for (int e = 0; e < 4; e++) {
                    __half2 pre = __hfma2(ds2, wv.h[e], __hadd2(av.h[e], bv.h[e]));
                    sv.h[e] = silu_h2(pre, kf, one2);
                }
                *(f16x8*)(Sc + row * 136 + col) = sv.v;
            }
            __syncthreads();
            // GEMM 64x16 tile: wave w cols c*16.., all 64 j rows (4 mb tiles)
            f32x4 acc[4];
#pragma unroll
            for (int mb = 0; mb < 4; mb++) acc[mb] = (f32x4){ eb2v, eb2v, eb2v, eb2v };
#pragma unroll
            for (int s = 0; s < 4; s++)
#pragma unroll
                for (int mb = 0; mb < 4; mb++) {
                    f16x8 af = *(const f16x8*)(Sc + (mb * 16 + m_) * 136 + s * 32 + q_ * 8);
                    acc[mb] = __builtin_amdgcn_mfma_f32_16x16x32_f16(af, bfr[s], acc[mb], 0, 0, 0);
                }
            // silu + mean over j (mb,r in-reg, q_ via shfl)
            float scv = 0.0f;
#pragma unroll
            for (int mb = 0; mb < 4; mb++)
#pragma unroll
                for (int r = 0; r < 4; r++)
                    scv += silu_f(acc[mb][r]);
            scv += __shfl_xor(scv, 16);
            scv += __shfl_xor(scv, 32);
            if (lane < 16)
                m_lds[i * 136 + c * 16 + lane] = (f16)(scv * (1.0f / 64.0f));
            // next i's build writes S[(i+1)&1]; this bar(i) + program order
            // make the double-buffer WAR-safe with one barrier per i.
        }
        __syncthreads();   // m_lds ready

        // ---- node (r13 structure, LDS-sourced) ----
        f16x8 af2[8];
#pragma unroll
        for (int s = 0; s < 4; s++) {
            af2[s]     = *(const f16x8*)(h_lds + m_ * 136 + s * 32 + q_ * 8);
            af2[s + 4] = *(const f16x8*)(m_lds + m_ * 136 + s * 32 + q_ * 8);
        }
        f16* relay = &S[0][0];             // S idle during node
        {
            float e = nb1C[c * 16 + m_];
            f32x4 acc = { e, e, e, e };
#pragma unroll
            for (int s = 0; s < 8; s++) {
                f16x8 bv = *(const f16x8*)(nw1s + ((s * 8 + c) * 64 + lane) * 8);
                acc = __builtin_amdgcn_mfma_f32_16x16x32_f16(af2[s], bv, acc, 0, 0, 0);
            }
#pragma unroll
            for (int r = 0; r < 4; r++)
                relay[(q_ * 4 + r) * 136 + c * 16 + m_] = (f16)silu_f(acc[r]);
        }
        __syncthreads();
        f16x8 uf[4];
#pragma unroll
        for (int s = 0; s < 4; s++)
            uf[s] = *(const f16x8*)(relay + m_ * 136 + s * 32 + q_ * 8);
        float x[4];
        {
            float e = nb2C[c * 16 + m_];
            f32x4 acc = { e, e, e, e };
#pragma unroll
            for (int s = 0; s < 4; s++) {
                f16x8 bv = *(const f16x8*)(nw2s + ((s * 8 + c) * 64 + lane) * 8);
                acc = __builtin_amdgcn_mfma_f32_16x16x32_f16(uf[s], bv, acc, 0, 0, 0);
            }
#pragma unroll
            for (int r = 0; r < 4; r++)
                x[r] = acc[r] + (float)h_lds[(q_ * 4 + r) * 136 + c * 16 + m_];
        }
        float s1p[4], s2p[4];
#pragma unroll
        for (int r = 0; r < 4; r++) { s1p[r] = x[r]; s2p[r] = x[r] * x[r]; }
#pragma unroll
        for (int msk = 1; msk < 16; msk <<= 1)
#pragma unroll
            for (int r = 0; r < 4; r++) {
                s1p[r] += __shfl_xor(s1p[r], msk);
                s2p[r] += __shfl_xor(s2p[r], msk);
            }
        if (m_ == 0)
#pragma unroll
            for (int r = 0; r < 4; r++) {
                s1sh[w][q_ * 4 + r] = s1p[r];
                s2sh[w][q_ * 4 + r] = s2p[r];
            }
        __syncthreads();
        float mu[4], rs[4];
#pragma unroll
        for (int r = 0; r < 4; r++) {
            int row = q_ * 4 + r;
            float S1 = 0.0f, S2 = 0.0f;
#pragma unroll
            for (int w2 = 0; w2 < 8; w2++) { S1 += s1sh[w2][row]; S2 += s2sh[w2][row]; }
            mu[r] = S1 * (1.0f / 128.0f);
            float var = S2 * (1.0f / 128.0f) - mu[r] * mu[r];
            rs[r] = rsqrtf(var + 1e-5f);
        }

        if (lay < 3) {
#pragma unroll
            for (int r = 0; r < 4; r++) {
                int col = c * 16 + m_;
                float y = (x[r] - mu[r]) * rs[r] * lngC[col] + lnbC[col];
                h_lds[(q_ * 4 + r) * 136 + col] = (f16)y;
            }
            __syncthreads();
            f16x8 hf[4];
#pragma unroll
            for (int s = 0; s < 4; s++)
                hf[s] = *(const f16x8*)(h_lds + m_ * 136 + s * 32 + q_ * 8);
            const f16* wlN = Wswz + (lay + 1) * 98304;
            const float* eb1N = sc + 14080 + (lay + 1) * 128;
#pragma unroll
            for (int mat = 0; mat < 2; mat++) {
                const f16* W = mat ? (wlN + 16384) : wlN;
                float init = mat ? 0.0f : eb1N[c * 16 + m_];
                f32x4 acc = { init, init, init, init };
#pragma unroll
                for (int s = 0; s < 4; s++) {
                    f16x8 bv = *(const f16x8*)(W + ((s * 8 + c) * 64 + lane) * 8);
                    acc = __builtin_amdgcn_mfma_f32_16x16x32_f16(hf[s], bv, acc, 0, 0, 0);
                }
#pragma unroll
                for (int r = 0; r < 4; r++) {
                    if (mat == 0)
                        a_lds[(q_ * 4 + r) * 136 + c * 16 + m_] = (f16)acc[r];
                    else
                        bnxt[(r0 + q_ * 4 + r) * 128 + c * 16 + m_] = (f16)acc[r];
                }
            }
            __syncthreads();
            if (t == 0) {
                __threadfence();
                __hip_atomic_fetch_add(&flags[b], 1, __ATOMIC_RELEASE,
                                       __HIP_MEMORY_SCOPE_AGENT);
            }
        } else {
            // final: LN + out projection (dsq2 dead -> reuse as psh)
            const float* owC = sc + 17152;
            const float* obC = sc + 17536;
            float (*psh)[16][3] = (float (*)[16][3])(void*)dsq2;
            float p[3][4];
#pragma unroll
            for (int r = 0; r < 4; r++) {
                int col = c * 16 + m_;
                float y = (x[r] - mu[r]) * rs[r] * lngC[col] + lnbC[col];
                p[0][r] = y * owC[col * 3 + 0];
                p[1][r] = y * owC[col * 3 + 1];
                p[2][r] = y * owC[col * 3 + 2];
            }
#pragma unroll
            for (int msk = 1; msk < 16; msk <<= 1)
#pragma unroll
                for (int k = 0; k < 3; k++)
#pragma unroll
                    for (int r = 0; r < 4; r++)
                        p[k][r] += __shfl_xor(p[k][r], msk);
            if (m_ == 0)
#pragma unroll
                for (int r = 0; r < 4; r++)
#pragma unroll
                    for (int k = 0; k < 3; k++)
                        psh[w][q_ * 4 + r][k] = p[k][r];
            __syncthreads();
            if (t < 16) {
                int row = r0 + t;
                int bf = flgsh;
#pragma unroll
                for (int k = 0; k < 3; k++) {
                    float v = obC[k];
#pragma unroll
                    for (int w2 = 0; w2 < 8; w2++) v += psh[w2][t][k];
                    if (bf) ((unsigned short*)out)[row * 3 + k] = f2bf(v);
                    else    ((float*)out)[row * 3 + k] = v;
                }
            }
        }
    }
}

extern "C" void kernel_launch(void* const* d_in, const int* in_sizes, int n_in,
                              void* d_out, int out_size, void* d_ws, size_t ws_size,
                              hipStream_t stream)
{
    char* ws = (char*)d_ws;
    int*   flags = (int*)ws;                        // 256 B
    float* sc    = (float*)(ws + 1024);             // 70 KB
    f16*   Wswz  = (f16*)(ws + (128u << 10));       // 768 KB
    f16*   b0    = (f16*)(ws + (1u << 20));         // 1 MB
    f16*   b1    = (f16*)(ws + (2u << 20));         // 1 MB

    Ptrs ptrs;
    const int src_idx[14] = {0, 2, 3, 4, 5, 6, 7, 8, 9, 10, 11, 12, 13, 14};
    for (int k = 0; k < 14; k++) ptrs.p[k] = d_in[src_idx[k]];

    prep_kernel<<<1605, 256, 0, stream>>>(ptrs, Wswz, sc, flags);
    net_kernel<<<256, 512, 0, stream>>>(d_in[0], (const int*)d_in[1],
                                        sc, Wswz, b0, b1, flags, d_out);
}